// Round 10
// baseline (1118.109 us; speedup 1.0000x reference)
//
#include <hip/hip_runtime.h>
#include <math.h>

#ifndef M_PI
#define M_PI 3.14159265358979323846
#endif

typedef __attribute__((ext_vector_type(8))) short bf16x8;
typedef __attribute__((ext_vector_type(4))) float f32x4;

struct CwtP {
  double sstep[8];
  float  sqs[8];
  int    L[8];
  int    st0[8];
};

// ---- workspace byte-offset map (high-water ~30.9 MB) ----
#define OFF_DTABC 0
#define OFF_DTABS 5376
#define OFF_AMP   10752
#define OFF_DCT   32320
#define OFF_DFILT 43072
#define OFF_PW    51520
#define OFF_META  51616
#define OFF_B1    51712
#define OFF_B2    51968
#define OFF_W1T   52224
#define OFF_W2T   547840
#define OFF_XT    1043456
#define OFF_PADW  1731584
#define OFF_PADW2 8016896
#define OFF_WRC2  20587520
#define OFF_POUT2 26092544
#define OFF_OUT1T 30221312
// aliases (live ranges disjoint):
#define OFF_PADP  OFF_PADW
#define OFF_PADP2 OFF_PADW2
#define OFF_LN    26092544
#define OFF_HB    26780672
#define OFF_OUT2T 28156928

__device__ inline unsigned short f2b(float f) {
  unsigned int u = __float_as_uint(f);
  unsigned int r = (u + 0x7fffu + ((u >> 16) & 1u)) >> 16;
  return (unsigned short)r;
}

__global__ void k_tables(double* __restrict__ dtabc, double* __restrict__ dtabs,
                         float* __restrict__ dcttab) {
  int tid = threadIdx.x;
  for (int j = tid; j < 672; j += blockDim.x) {
    double a = (2.0 * M_PI * (double)j) / 672.0;
    dtabc[j] = cos(a);
    dtabs[j] = sin(a);
  }
  for (int j = tid; j < 2688; j += blockDim.x) {
    dcttab[j] = (float)cos(M_PI * (double)j / 1344.0);
  }
}

// mean-of-6 masked weights -> bf16 tap-major layouts:
// W1T[tap][co(64)][ci(32)], W2T[tap][co(32)][ci(64)]; biases fp32
__global__ void k_wmeanb(const float* __restrict__ w1, const float* __restrict__ b1,
                         const float* __restrict__ w2, const float* __restrict__ b2,
                         unsigned short* __restrict__ W1T, unsigned short* __restrict__ W2T,
                         float* __restrict__ B1, float* __restrict__ B2) {
  int i = blockIdx.x * blockDim.x + threadIdx.x;
  const float inv6 = 1.0f / 6.0f;
  if (i < 247808) {
    float s1 = 0.f, s2 = 0.f;
#pragma unroll
    for (int g = 0; g < 6; ++g) { s1 += w1[g * 247808 + i]; s2 += w2[g * 247808 + i]; }
    s1 *= inv6; s2 *= inv6;
    {
      int co = i / 3872; int r = i - co * 3872;
      int ci = r / 121;  int tap = r - ci * 121;
      W1T[tap * 2048 + co * 32 + ci] = f2b(s1);
    }
    {
      int co = i / 7744; int r = i - co * 7744;
      int ci = r / 121;  int tap = r - ci * 121;
      W2T[tap * 2048 + co * 64 + ci] = f2b(s2);
    }
  } else {
    int j = i - 247808;
    if (j < 64) {
      float s = 0.f;
#pragma unroll
      for (int g = 0; g < 6; ++g) s += b1[g * 64 + j];
      B1[j] = s * inv6;
    } else if (j < 96) {
      int c = j - 64;
      float s = 0.f;
#pragma unroll
      for (int g = 0; g < 6; ++g) s += b2[g * 32 + c];
      B2[c] = s * inv6;
    }
  }
}

__global__ void k_xT(const float* __restrict__ x, float* __restrict__ xT) {
  int i = blockIdx.x * 256 + threadIdx.x;
  if (i >= 8 * 672 * 32) return;
  int n = i & 31;
  int t = (i >> 5) % 672;
  int b = i / (32 * 672);
  xT[(b * 32 + n) * 672 + t] = x[i];
}

__global__ void k_dft(const float* __restrict__ x, const double* __restrict__ tc,
                      const double* __restrict__ ts, double* __restrict__ amp) {
  int k = blockIdx.x, b = blockIdx.y;
  int tid = threadIdx.x;
  int n = tid & 31, half = tid >> 5;
  double re = 0.0, im = 0.0;
  for (int t = half; t < 672; t += 2) {
    double xv = (double)x[(b * 672 + t) * 32 + n];
    int idx = (k * t) % 672;
    re += xv * tc[idx];
    im += xv * ts[idx];
  }
  re += __shfl_xor(re, 32);
  im += __shfl_xor(im, 32);
  double a = sqrt(re * re + im * im);
  for (int off = 16; off >= 1; off >>= 1) a += __shfl_xor(a, off);
  if (tid == 0) amp[b * 337 + k] = a * (1.0 / 32.0);
}

__global__ void k_top(const double* __restrict__ amp, int* __restrict__ meta,
                      float* __restrict__ pw) {
  __shared__ double fr[337];
  __shared__ int sidx[3];
  int tid = threadIdx.x;
  for (int k = tid; k < 337; k += 64) {
    double s = 0.0;
    for (int b = 0; b < 8; ++b) s += amp[b * 337 + k];
    fr[k] = (k == 0) ? -1.0 : s * 0.125;
  }
  __syncthreads();
  if (tid == 0) {
    for (int r = 0; r < 3; ++r) {
      int best = 1; double bv = fr[1];
      for (int k = 2; k < 337; ++k) if (fr[k] > bv) { bv = fr[k]; best = k; }
      fr[best] = -2.0;
      sidx[r] = best;
      meta[r] = best;
      int p = 672 / best;
      meta[3 + r] = p;                     // W
      int len = (672 % p == 0) ? 672 : (672 / p + 1) * p;
      meta[6 + r] = len;
      meta[9 + r] = len / p;               // H
    }
  }
  __syncthreads();
  if (tid < 8) {
    int b = tid;
    float v0 = (float)amp[b * 337 + sidx[0]];
    float v1 = (float)amp[b * 337 + sidx[1]];
    float v2 = (float)amp[b * 337 + sidx[2]];
    float m = fmaxf(v0, fmaxf(v1, v2));
    float e0 = expf(v0 - m), e1 = expf(v1 - m), e2 = expf(v2 - m);
    float inv = 1.0f / (e0 + e1 + e2);
    pw[b * 3 + 0] = e0 * inv;
    pw[b * 3 + 1] = e1 * inv;
    pw[b * 3 + 2] = e2 * inv;
  }
}

// parallel psi integration: 1024 threads, Hillis-Steele scan in LDS
__global__ void k_dfilt(float* __restrict__ dfilt, CwtP P) {
  __shared__ double ipsi[1024];
  int tid = threadIdx.x;
  const double step = 16.0 / 1023.0;
  double xg = (tid == 1023) ? 8.0 : (-8.0 + (double)tid * step);
  ipsi[tid] = exp(-0.5 * xg * xg) * cos(5.0 * xg);
  __syncthreads();
  for (int off = 1; off < 1024; off <<= 1) {
    double v = ipsi[tid];
    double a = (tid >= off) ? ipsi[tid - off] : 0.0;
    __syncthreads();
    ipsi[tid] = v + a;
    __syncthreads();
  }
  for (int s = 0; s < 8; ++s) {
    int L = P.L[s];
    double sstep = P.sstep[s];
    for (int q = tid; q <= L; q += 1024) {
      float fq = 0.f, fqm = 0.f;
      if (q < L)  { long j = (long)((double)(L - 1 - q) / sstep); fq  = (float)(ipsi[j] * step); }
      if (q >= 1) { long j = (long)((double)(L - q) / sstep);     fqm = (float)(ipsi[j] * step); }
      dfilt[s * 264 + q] = fq - fqm;
    }
  }
}

// CWT -> zero-padded bf16 image PADW[b][s+5][t+5][n], PH=18, PW=682
__global__ void k_cwt(const float* __restrict__ xT, const float* __restrict__ dfilt,
                      unsigned short* __restrict__ PADW, CwtP P) {
  int s = blockIdx.x, n = blockIdx.y, b = blockIdx.z;
  __shared__ float row[672];
  __shared__ float df[264];
  int tid = threadIdx.x;
  int L = P.L[s], st0 = P.st0[s];
  float sq = P.sqs[s];
  for (int i = tid; i < 672; i += blockDim.x) row[i] = xT[(b * 32 + n) * 672 + i];
  for (int i = tid; i <= L; i += blockDim.x) df[i] = dfilt[s * 264 + i];
  __syncthreads();
  for (int t = tid; t < 672; t += blockDim.x) {
    float acc = 0.f;
    int base = t + st0 + 1;
    for (int q = 0; q <= L; ++q) {
      int idx = base - q;
      if (idx >= 0 && idx < 672) acc += df[q] * row[idx];
    }
    PADW[((size_t)(b * 18 + s + 5) * 682 + (t + 5)) * 32 + n] = f2b(-sq * acc);
  }
}

__global__ void k_zero(float4* __restrict__ p, int n16) {
  int i = blockIdx.x * 256 + threadIdx.x;
  int stride = gridDim.x * 256;
  for (; i < n16; i += stride) p[i] = float4{0.f, 0.f, 0.f, 0.f};
}

// fold x into zero-padded bf16 period image: PADP[b][h+5][w+5][ci], PW=W+10
__global__ void k_pfill(const float* __restrict__ x, unsigned short* __restrict__ PADP,
                        const int* __restrict__ meta, int k) {
  int i = blockIdx.x * 256 + threadIdx.x;
  if (i >= 8 * 672 * 32) return;
  int W = meta[3 + k], H = meta[9 + k];
  int PW = W + 10;
  int ci = i & 31;
  int t = (i >> 5) % 672;
  int b = i / 21504;
  int h = t / W, w = t - h * W;
  PADP[((size_t)(b * (H + 10) + h + 5) * PW + (w + 5)) * 32 + ci] = f2b(x[i]);
}

// Tap-decomposed implicit-GEMM conv via MFMA bf16, FLAT tiling + CO-SPLIT.
// Each wave owns ONE co-tile (c = wv % NCO) of one 16-position flat tile
// (ti = base + wv / NCO) and runs the FULL kh loop into a single f32x4 acc:
// no LDS, no barriers. Per (kh,s) the wave issues 11 B + 11 A independent
// 16B loads feeding 11 MFMAs -> ~22 outstanding loads/wave (the round-9
// VGPR=52 profile showed the old kh-split code serialized 1 load/MFMA).
// MODE 0: +bias, exact GELU, write bf16 into padded mid image [b][h+5][w+5][co]
// MODE 1: +bias, write fp32 flat [b][t][co] (t < Tlim only)
template <int CIN, int COUT, int MODE>
__global__ __launch_bounds__(256) void k_conv(
    const unsigned short* __restrict__ Pin, const unsigned short* __restrict__ Wt,
    const float* __restrict__ bias, void* __restrict__ outp,
    int Hs, int Ws, int gi, const int* __restrict__ meta, int HWcap, int Tlim) {
  constexpr int NCO = COUT / 16;       // co tiles (4 or 2)
  constexpr int TPB = 4 / NCO;         // position tiles per block (1 or 2)
  constexpr int NS = CIN / 32;         // k slices per tap

  int H = Hs, W = Ws;
  if (gi >= 0) { W = meta[3 + gi]; H = meta[9 + gi]; }
  int PW = W + 10;
  int HW = H * W;
  int Tout = (HW < Tlim) ? HW : Tlim;
  int tiles = (Tout + 15) >> 4;
  int tgroups = (tiles + TPB - 1) / TPB;
  int total = 8 * tgroups;
  int gid = blockIdx.x;
  if (gid >= total) return;
  // bijective round-robin -> chunked remap (8 XCDs), b-major chunks
  int q = total >> 3, rr = total & 7;
  int xcd = gid & 7, lid = gid >> 3;
  int wid = (xcd < rr) ? (xcd * (q + 1) + lid)
                       : (rr * (q + 1) + (xcd - rr) * q + lid);
  int tg = wid % tgroups; int b = wid / tgroups;
  int wv = threadIdx.x >> 6;
  int l = threadIdx.x & 63;
  int lr = l & 15, lk = l >> 4;

  int ti = tg * TPB + wv / NCO;
  int c  = wv % NCO;
  if (ti >= tiles) return;

  int t = ti * 16 + lr;
  bool valid = (t < Tout);
  unsigned tt = valid ? (unsigned)t : 0u;
  unsigned h = tt / (unsigned)W;
  unsigned w = tt - h * (unsigned)W;

  // kh taps that touch any real row for this tile's h-span
  int h0 = (ti * 16) / W;
  int tl5 = ti * 16 + 15; if (tl5 >= Tout) tl5 = Tout - 1;
  int h1 = tl5 / W;
  int kh_lo = (h1 >= 5) ? 0 : 5 - h1;
  int kh_hi = (H + 4 - h0 < 10) ? (H + 4 - h0) : 10;

  const unsigned short* pB =
      Pin + ((size_t)(b * (H + 10) + h) * PW + w) * CIN + lk * 8;
  const unsigned short* pAc =
      Wt + (size_t)c * 16 * CIN + (size_t)lr * CIN + lk * 8;

  f32x4 acc = f32x4{0.f, 0.f, 0.f, 0.f};

  for (int kh = kh_lo; kh <= kh_hi; ++kh) {
    const unsigned short* pBr = pB + (size_t)kh * PW * CIN;
    const unsigned short* pA = pAc + (size_t)(kh * 11) * COUT * CIN;
#pragma unroll
    for (int s = 0; s < NS; ++s) {
      bf16x8 bfr[11], afr[11];
#pragma unroll
      for (int kw = 0; kw < 11; ++kw) {
        bfr[kw] = *(const bf16x8*)(const void*)(pBr + kw * CIN + s * 32);
        afr[kw] = *(const bf16x8*)(const void*)(pA + (size_t)kw * COUT * CIN + s * 32);
      }
#pragma unroll
      for (int kw = 0; kw < 11; ++kw)
        acc = __builtin_amdgcn_mfma_f32_16x16x32_bf16(afr[kw], bfr[kw], acc, 0, 0, 0);
    }
  }

  if (!valid) return;
  int co0 = c * 16 + lk * 4;
  float v[4];
#pragma unroll
  for (int q2 = 0; q2 < 4; ++q2) {
    float s = acc[q2] + bias[co0 + q2];
    if (MODE == 0) s = 0.5f * s * (1.0f + erff(s * 0.70710678118654752f));
    v[q2] = s;
  }
  if (MODE == 0) {
    unsigned short* Po = (unsigned short*)outp;
    size_t oa = ((size_t)(b * (H + 10) + h + 5) * PW + (w + 5)) * COUT + co0;
    uint2 pk;
    pk.x = (unsigned int)f2b(v[0]) | ((unsigned int)f2b(v[1]) << 16);
    pk.y = (unsigned int)f2b(v[2]) | ((unsigned int)f2b(v[3]) << 16);
    *(uint2*)(void*)(Po + oa) = pk;
  } else {
    float* Fo = (float*)outp;
    size_t oa = ((size_t)b * HWcap + t) * COUT + co0;
    f32x4 vv = {v[0], v[1], v[2], v[3]};
    *(f32x4*)(void*)(Fo + oa) = vv;
  }
}

__global__ void k_combine(const float* __restrict__ WRC2, const float* __restrict__ w_scale,
                          const float* __restrict__ b_scale, const float* __restrict__ POUT2,
                          const float* __restrict__ pw, const float* __restrict__ xT,
                          float* __restrict__ out1T) {
  int b = blockIdx.y;
  int tid = threadIdx.x;
  int n = tid & 31;
  int t = blockIdx.x * 8 + (tid >> 5);
  float wv = b_scale[n];
#pragma unroll
  for (int s = 0; s < 8; ++s)
    wv += WRC2[((size_t)(b * 5376 + s * 672 + t)) * 32 + n] * w_scale[n * 8 + s];
  float p0 = pw[b * 3 + 0], p1 = pw[b * 3 + 1], p2 = pw[b * 3 + 2];
  size_t bi = (size_t)(b * 1344 + t) * 32 + n;
  float rs = p0 * POUT2[bi] + p1 * POUT2[344064 + bi] + p2 * POUT2[688128 + bi];
  const float pc10 = 1.0f / 1024.0f;
  out1T[(b * 32 + n) * 672 + t] =
      (1.0f - pc10) * wv + pc10 * rs + xT[(b * 32 + n) * 672 + t];
}

__global__ void k_dct_ln(const float* __restrict__ out1T, const float* __restrict__ dcttab,
                         const float* __restrict__ ln_w, const float* __restrict__ ln_b,
                         float* __restrict__ ln) {
  int c = blockIdx.x, b = blockIdx.y;
  __shared__ float row[672];
  __shared__ float tab[2688];
  __shared__ float s1[4], s2[4];
  int tid = threadIdx.x;
  for (int i = tid; i < 672; i += 256) row[i] = out1T[(b * 32 + c) * 672 + i];
  for (int i = tid; i < 2688; i += 256) tab[i] = dcttab[i];
  __syncthreads();
  float fv[3];
  float sum = 0.f, sumsq = 0.f;
#pragma unroll
  for (int r = 0; r < 3; ++r) {
    int k = tid + r * 256;
    float acc = 0.f;
    if (k < 672) {
      int idx = k;
      int stp = (2 * k) % 2688;
      for (int m = 0; m < 672; ++m) {
        acc += row[m] * tab[idx];
        idx += stp;
        if (idx >= 2688) idx -= 2688;
      }
      acc *= 2.0f;
      sum += acc;
      sumsq += acc * acc;
    }
    fv[r] = acc;
  }
  for (int off = 32; off >= 1; off >>= 1) {
    sum += __shfl_xor(sum, off);
    sumsq += __shfl_xor(sumsq, off);
  }
  if ((tid & 63) == 0) { s1[tid >> 6] = sum; s2[tid >> 6] = sumsq; }
  __syncthreads();
  float tsum = s1[0] + s1[1] + s1[2] + s1[3];
  float tsq = s2[0] + s2[1] + s2[2] + s2[3];
  float mu = tsum * (1.0f / 672.0f);
  float var = tsq * (1.0f / 672.0f) - mu * mu;
  float rstd = rsqrtf(var + 1e-6f);
#pragma unroll
  for (int r = 0; r < 3; ++r) {
    int k = tid + r * 256;
    if (k < 672)
      ln[(b * 32 + c) * 672 + k] = (fv[r] - mu) * rstd * ln_w[k] + ln_b[k];
  }
}

__global__ void k_fc1(const float* __restrict__ ln, const float* __restrict__ w_fc1,
                      float* __restrict__ h) {
  int d = blockIdx.x, b = blockIdx.y;
  int tid = threadIdx.x;
  __shared__ float wv[32];
  if (tid < 32) wv[tid] = w_fc1[d * 32 + tid];
  __syncthreads();
  for (int t = tid; t < 672; t += 256) {
    float s = 0.f;
#pragma unroll
    for (int c = 0; c < 32; ++c) s += ln[(b * 32 + c) * 672 + t] * wv[c];
    h[(b * 64 + d) * 672 + t] = fmaxf(s, 0.f);
  }
}

__global__ void k_fc2o(const float* __restrict__ h, const float* __restrict__ w_fc2,
                       const float* __restrict__ out1T, const float* __restrict__ xT,
                       float* __restrict__ out2T) {
  int c = blockIdx.x, b = blockIdx.y;
  int tid = threadIdx.x;
  __shared__ float wv[64];
  if (tid < 64) wv[tid] = w_fc2[c * 64 + tid];
  __syncthreads();
  for (int t = tid; t < 672; t += 256) {
    float s = 0.f;
#pragma unroll
    for (int d = 0; d < 64; ++d) s += h[(b * 64 + d) * 672 + t] * wv[d];
    float lr = 1.0f / (1.0f + expf(-s));
    out2T[(b * 32 + c) * 672 + t] =
        out1T[(b * 32 + c) * 672 + t] * lr + xT[(b * 32 + c) * 672 + t];
  }
}

__global__ void k_proj(const float* __restrict__ out2T, const float* __restrict__ w_proj,
                       const float* __restrict__ b_proj, float* __restrict__ out) {
  int p = blockIdx.x, b = blockIdx.y;
  int tid = threadIdx.x;
  int n = tid & 31, half = tid >> 5;
  float acc = 0.f;
  for (int t = half; t < 672; t += 2)
    acc += out2T[(b * 32 + n) * 672 + t] * w_proj[p * 672 + t];
  acc += __shfl_xor(acc, 32);
  if (tid < 32) out[(b * 336 + p) * 32 + n] = acc + b_proj[p];
}

extern "C" void kernel_launch(void* const* d_in, const int* in_sizes, int n_in,
                              void* d_out, int out_size, void* d_ws, size_t ws_size,
                              hipStream_t stream) {
  (void)in_sizes; (void)n_in; (void)out_size; (void)ws_size;
  const float* x      = (const float*)d_in[0];
  const float* w_inc1 = (const float*)d_in[1];
  const float* b_inc1 = (const float*)d_in[2];
  const float* w_inc2 = (const float*)d_in[3];
  const float* b_inc2 = (const float*)d_in[4];
  const float* w_scale= (const float*)d_in[5];
  const float* b_scale= (const float*)d_in[6];
  const float* ln_w   = (const float*)d_in[7];
  const float* ln_b   = (const float*)d_in[8];
  const float* w_fc1  = (const float*)d_in[9];
  const float* w_fc2  = (const float*)d_in[10];
  const float* w_proj = (const float*)d_in[11];
  const float* b_proj = (const float*)d_in[12];
  float* out = (float*)d_out;

  char* ws = (char*)d_ws;
  double* dtabc = (double*)(ws + OFF_DTABC);
  double* dtabs = (double*)(ws + OFF_DTABS);
  double* amp   = (double*)(ws + OFF_AMP);
  float* dcttab = (float*)(ws + OFF_DCT);
  float* dfilt  = (float*)(ws + OFF_DFILT);
  float* pw     = (float*)(ws + OFF_PW);
  int*   meta   = (int*)(ws + OFF_META);
  float* B1     = (float*)(ws + OFF_B1);
  float* B2     = (float*)(ws + OFF_B2);
  unsigned short* W1T = (unsigned short*)(ws + OFF_W1T);
  unsigned short* W2T = (unsigned short*)(ws + OFF_W2T);
  float* xT     = (float*)(ws + OFF_XT);
  unsigned short* PADW  = (unsigned short*)(ws + OFF_PADW);
  unsigned short* PADW2 = (unsigned short*)(ws + OFF_PADW2);
  unsigned short* PADP  = (unsigned short*)(ws + OFF_PADP);
  unsigned short* PADP2 = (unsigned short*)(ws + OFF_PADP2);
  float* WRC2  = (float*)(ws + OFF_WRC2);
  float* POUT2 = (float*)(ws + OFF_POUT2);
  float* out1T = (float*)(ws + OFF_OUT1T);
  float* lnb   = (float*)(ws + OFF_LN);
  float* hb    = (float*)(ws + OFF_HB);
  float* out2T = (float*)(ws + OFF_OUT2T);

  // host-side CWT geometry (replicates numpy double arithmetic)
  CwtP P;
  const double step = 16.0 / 1023.0;
  for (int i = 0; i < 8; ++i) {
    double e = (i == 7) ? 4.0 : (-1.0 + (double)i * (5.0 / 7.0));
    double s = pow(2.0, e);
    double sstep = s * step;
    int Na = (int)ceil(16.0 * s + 1.0);
    int L = 0;
    for (int k = 0; k < Na; ++k) {
      long j = (long)((double)k / sstep);
      if (j < 1024) L++;
      else break;
    }
    P.sstep[i] = sstep;
    P.L[i] = L;
    P.st0[i] = (L - 2) / 2;
    P.sqs[i] = (float)sqrt(s);
  }

  k_tables<<<1, 256, 0, stream>>>(dtabc, dtabs, dcttab);
  k_wmeanb<<<(247808 + 96 + 255) / 256, 256, 0, stream>>>(w_inc1, b_inc1, w_inc2, b_inc2,
                                                          W1T, W2T, B1, B2);
  k_xT<<<672, 256, 0, stream>>>(x, xT);
  k_dfilt<<<1, 1024, 0, stream>>>(dfilt, P);
  k_dft<<<dim3(337, 8), 64, 0, stream>>>(x, dtabc, dtabs, amp);
  k_top<<<1, 64, 0, stream>>>(amp, meta, pw);

  // wavelet branch: H=8, W=672 -> conv1: 8*336 blocks; conv2: 8*168 blocks
  k_zero<<<2048, 256, 0, stream>>>((float4*)(ws + OFF_PADW), 1178496);  // PADW+PADW2
  k_cwt<<<dim3(8, 32, 8), 256, 0, stream>>>(xT, dfilt, PADW, P);
  k_conv<32, 64, 0><<<2688, 256, 0, stream>>>(PADW, W1T, B1, (void*)PADW2,
                                              8, 672, -1, meta, 0, 1 << 30);
  k_conv<64, 32, 1><<<1344, 256, 0, stream>>>(PADW2, W2T, B2, (void*)WRC2,
                                              8, 672, -1, meta, 5376, 1 << 30);

  // period branch: conv1 <= 8*84=672 blocks; conv2 = 8*21=168 (t<672)
  for (int k = 0; k < 3; ++k) {
    k_zero<<<1024, 256, 0, stream>>>((float4*)(ws + OFF_PADP), 240064);
    k_zero<<<2048, 256, 0, stream>>>((float4*)(ws + OFF_PADP2), 480128);
    k_pfill<<<672, 256, 0, stream>>>(x, PADP, meta, k);
    k_conv<32, 64, 0><<<672, 256, 0, stream>>>(PADP, W1T, B1, (void*)PADP2,
                                               0, 0, k, meta, 0, 1 << 30);
    k_conv<64, 32, 1><<<168, 256, 0, stream>>>(PADP2, W2T, B2,
                                               (void*)(POUT2 + (size_t)k * 344064),
                                               0, 0, k, meta, 1344, 672);
  }

  k_combine<<<dim3(84, 8), 256, 0, stream>>>(WRC2, w_scale, b_scale, POUT2, pw, xT, out1T);
  k_dct_ln<<<dim3(32, 8), 256, 0, stream>>>(out1T, dcttab, ln_w, ln_b, lnb);
  k_fc1<<<dim3(64, 8), 256, 0, stream>>>(lnb, w_fc1, hb);
  k_fc2o<<<dim3(32, 8), 256, 0, stream>>>(hb, w_fc2, out1T, xT, out2T);
  k_proj<<<dim3(336, 8), 64, 0, stream>>>(out2T, w_proj, b_proj, out);
}

// Round 11
// 1109.412 us; speedup vs baseline: 1.0078x; 1.0078x over previous
//
#include <hip/hip_runtime.h>
#include <math.h>

#ifndef M_PI
#define M_PI 3.14159265358979323846
#endif

typedef __attribute__((ext_vector_type(8))) short bf16x8;
typedef __attribute__((ext_vector_type(4))) float f32x4;

struct CwtP {
  double sstep[8];
  float  sqs[8];
  int    L[8];
  int    st0[8];
};

// ---- workspace byte-offset map (high-water ~30.9 MB) ----
#define OFF_DTABC 0
#define OFF_DTABS 5376
#define OFF_AMP   10752
#define OFF_DCT   32320
#define OFF_DFILT 43072
#define OFF_PW    51520
#define OFF_META  51616
#define OFF_B1    51712
#define OFF_B2    51968
#define OFF_W1T   52224
#define OFF_W2T   547840
#define OFF_XT    1043456
#define OFF_PADW  1731584
#define OFF_PADW2 8016896
#define OFF_WRC2  20587520
#define OFF_POUT2 26092544
#define OFF_OUT1T 30221312
// aliases (live ranges disjoint):
#define OFF_PADP  OFF_PADW
#define OFF_PADP2 OFF_PADW2
#define OFF_LN    26092544
#define OFF_HB    26780672
#define OFF_OUT2T 28156928

__device__ inline unsigned short f2b(float f) {
  unsigned int u = __float_as_uint(f);
  unsigned int r = (u + 0x7fffu + ((u >> 16) & 1u)) >> 16;
  return (unsigned short)r;
}

__global__ void k_tables(double* __restrict__ dtabc, double* __restrict__ dtabs,
                         float* __restrict__ dcttab) {
  int tid = threadIdx.x;
  for (int j = tid; j < 672; j += blockDim.x) {
    double a = (2.0 * M_PI * (double)j) / 672.0;
    dtabc[j] = cos(a);
    dtabs[j] = sin(a);
  }
  for (int j = tid; j < 2688; j += blockDim.x) {
    dcttab[j] = (float)cos(M_PI * (double)j / 1344.0);
  }
}

// mean-of-6 masked weights -> bf16 tap-major layouts:
// W1T[tap][co(64)][ci(32)], W2T[tap][co(32)][ci(64)]; biases fp32
__global__ void k_wmeanb(const float* __restrict__ w1, const float* __restrict__ b1,
                         const float* __restrict__ w2, const float* __restrict__ b2,
                         unsigned short* __restrict__ W1T, unsigned short* __restrict__ W2T,
                         float* __restrict__ B1, float* __restrict__ B2) {
  int i = blockIdx.x * blockDim.x + threadIdx.x;
  const float inv6 = 1.0f / 6.0f;
  if (i < 247808) {
    float s1 = 0.f, s2 = 0.f;
#pragma unroll
    for (int g = 0; g < 6; ++g) { s1 += w1[g * 247808 + i]; s2 += w2[g * 247808 + i]; }
    s1 *= inv6; s2 *= inv6;
    {
      int co = i / 3872; int r = i - co * 3872;
      int ci = r / 121;  int tap = r - ci * 121;
      W1T[tap * 2048 + co * 32 + ci] = f2b(s1);
    }
    {
      int co = i / 7744; int r = i - co * 7744;
      int ci = r / 121;  int tap = r - ci * 121;
      W2T[tap * 2048 + co * 64 + ci] = f2b(s2);
    }
  } else {
    int j = i - 247808;
    if (j < 64) {
      float s = 0.f;
#pragma unroll
      for (int g = 0; g < 6; ++g) s += b1[g * 64 + j];
      B1[j] = s * inv6;
    } else if (j < 96) {
      int c = j - 64;
      float s = 0.f;
#pragma unroll
      for (int g = 0; g < 6; ++g) s += b2[g * 32 + c];
      B2[c] = s * inv6;
    }
  }
}

__global__ void k_xT(const float* __restrict__ x, float* __restrict__ xT) {
  int i = blockIdx.x * 256 + threadIdx.x;
  if (i >= 8 * 672 * 32) return;
  int n = i & 31;
  int t = (i >> 5) % 672;
  int b = i / (32 * 672);
  xT[(b * 32 + n) * 672 + t] = x[i];
}

__global__ void k_dft(const float* __restrict__ x, const double* __restrict__ tc,
                      const double* __restrict__ ts, double* __restrict__ amp) {
  int k = blockIdx.x, b = blockIdx.y;
  int tid = threadIdx.x;
  int n = tid & 31, half = tid >> 5;
  double re = 0.0, im = 0.0;
  for (int t = half; t < 672; t += 2) {
    double xv = (double)x[(b * 672 + t) * 32 + n];
    int idx = (k * t) % 672;
    re += xv * tc[idx];
    im += xv * ts[idx];
  }
  re += __shfl_xor(re, 32);
  im += __shfl_xor(im, 32);
  double a = sqrt(re * re + im * im);
  for (int off = 16; off >= 1; off >>= 1) a += __shfl_xor(a, off);
  if (tid == 0) amp[b * 337 + k] = a * (1.0 / 32.0);
}

__global__ void k_top(const double* __restrict__ amp, int* __restrict__ meta,
                      float* __restrict__ pw) {
  __shared__ double fr[337];
  __shared__ int sidx[3];
  int tid = threadIdx.x;
  for (int k = tid; k < 337; k += 64) {
    double s = 0.0;
    for (int b = 0; b < 8; ++b) s += amp[b * 337 + k];
    fr[k] = (k == 0) ? -1.0 : s * 0.125;
  }
  __syncthreads();
  if (tid == 0) {
    for (int r = 0; r < 3; ++r) {
      int best = 1; double bv = fr[1];
      for (int k = 2; k < 337; ++k) if (fr[k] > bv) { bv = fr[k]; best = k; }
      fr[best] = -2.0;
      sidx[r] = best;
      meta[r] = best;
      int p = 672 / best;
      meta[3 + r] = p;                     // W
      int len = (672 % p == 0) ? 672 : (672 / p + 1) * p;
      meta[6 + r] = len;
      meta[9 + r] = len / p;               // H
    }
  }
  __syncthreads();
  if (tid < 8) {
    int b = tid;
    float v0 = (float)amp[b * 337 + sidx[0]];
    float v1 = (float)amp[b * 337 + sidx[1]];
    float v2 = (float)amp[b * 337 + sidx[2]];
    float m = fmaxf(v0, fmaxf(v1, v2));
    float e0 = expf(v0 - m), e1 = expf(v1 - m), e2 = expf(v2 - m);
    float inv = 1.0f / (e0 + e1 + e2);
    pw[b * 3 + 0] = e0 * inv;
    pw[b * 3 + 1] = e1 * inv;
    pw[b * 3 + 2] = e2 * inv;
  }
}

// parallel psi integration: 1024 threads, Hillis-Steele scan in LDS
__global__ void k_dfilt(float* __restrict__ dfilt, CwtP P) {
  __shared__ double ipsi[1024];
  int tid = threadIdx.x;
  const double step = 16.0 / 1023.0;
  double xg = (tid == 1023) ? 8.0 : (-8.0 + (double)tid * step);
  ipsi[tid] = exp(-0.5 * xg * xg) * cos(5.0 * xg);
  __syncthreads();
  for (int off = 1; off < 1024; off <<= 1) {
    double v = ipsi[tid];
    double a = (tid >= off) ? ipsi[tid - off] : 0.0;
    __syncthreads();
    ipsi[tid] = v + a;
    __syncthreads();
  }
  for (int s = 0; s < 8; ++s) {
    int L = P.L[s];
    double sstep = P.sstep[s];
    for (int q = tid; q <= L; q += 1024) {
      float fq = 0.f, fqm = 0.f;
      if (q < L)  { long j = (long)((double)(L - 1 - q) / sstep); fq  = (float)(ipsi[j] * step); }
      if (q >= 1) { long j = (long)((double)(L - q) / sstep);     fqm = (float)(ipsi[j] * step); }
      dfilt[s * 264 + q] = fq - fqm;
    }
  }
}

// CWT -> zero-padded bf16 image PADW[b][s+5][t+5][n], PH=18, PW=682
__global__ void k_cwt(const float* __restrict__ xT, const float* __restrict__ dfilt,
                      unsigned short* __restrict__ PADW, CwtP P) {
  int s = blockIdx.x, n = blockIdx.y, b = blockIdx.z;
  __shared__ float row[672];
  __shared__ float df[264];
  int tid = threadIdx.x;
  int L = P.L[s], st0 = P.st0[s];
  float sq = P.sqs[s];
  for (int i = tid; i < 672; i += blockDim.x) row[i] = xT[(b * 32 + n) * 672 + i];
  for (int i = tid; i <= L; i += blockDim.x) df[i] = dfilt[s * 264 + i];
  __syncthreads();
  for (int t = tid; t < 672; t += blockDim.x) {
    float acc = 0.f;
    int base = t + st0 + 1;
    for (int q = 0; q <= L; ++q) {
      int idx = base - q;
      if (idx >= 0 && idx < 672) acc += df[q] * row[idx];
    }
    PADW[((size_t)(b * 18 + s + 5) * 682 + (t + 5)) * 32 + n] = f2b(-sq * acc);
  }
}

__global__ void k_zero(float4* __restrict__ p, int n16) {
  int i = blockIdx.x * 256 + threadIdx.x;
  int stride = gridDim.x * 256;
  for (; i < n16; i += stride) p[i] = float4{0.f, 0.f, 0.f, 0.f};
}

// fold x into zero-padded bf16 period image: PADP[b][h+5][w+5][ci], PW=W+10
__global__ void k_pfill(const float* __restrict__ x, unsigned short* __restrict__ PADP,
                        const int* __restrict__ meta, int k) {
  int i = blockIdx.x * 256 + threadIdx.x;
  if (i >= 8 * 672 * 32) return;
  int W = meta[3 + k], H = meta[9 + k];
  int PW = W + 10;
  int ci = i & 31;
  int t = (i >> 5) % 672;
  int b = i / 21504;
  int h = t / W, w = t - h * W;
  PADP[((size_t)(b * (H + 10) + h + 5) * PW + (w + 5)) * 32 + ci] = f2b(x[i]);
}

// Tap-decomposed implicit-GEMM conv via MFMA bf16, FLAT tiling + CO-SPLIT,
// with PER-KH FRAGMENT BATCHING under a relaxed VGPR budget.
// __launch_bounds__(256, 2) lifts the VGPR cap to 256: per kh iteration ALL
// NS*11 B-fragments and NS*11 A-fragments are loaded into registers (22-44
// independent 16B loads in flight), then the MFMA chain runs on two
// accumulators (even/odd kw) to halve the dependent-MFMA latency chain.
// Rounds 8-10 showed the compiler's default occupancy heuristic capped
// VGPR at ~48 and serialized one load per MFMA (MfmaUtil ~3%).
// MODE 0: +bias, exact GELU, write bf16 into padded mid image [b][h+5][w+5][co]
// MODE 1: +bias, write fp32 flat [b][t][co] (t < Tlim only)
template <int CIN, int COUT, int MODE>
__global__ __launch_bounds__(256, 2) void k_conv(
    const unsigned short* __restrict__ Pin, const unsigned short* __restrict__ Wt,
    const float* __restrict__ bias, void* __restrict__ outp,
    int Hs, int Ws, int gi, const int* __restrict__ meta, int HWcap, int Tlim) {
  constexpr int NCO = COUT / 16;       // co tiles (4 or 2)
  constexpr int TPB = 4 / NCO;         // position tiles per block (1 or 2)
  constexpr int NS = CIN / 32;         // k slices per tap

  int H = Hs, W = Ws;
  if (gi >= 0) { W = meta[3 + gi]; H = meta[9 + gi]; }
  int PW = W + 10;
  int HW = H * W;
  int Tout = (HW < Tlim) ? HW : Tlim;
  int tiles = (Tout + 15) >> 4;
  int tgroups = (tiles + TPB - 1) / TPB;
  int total = 8 * tgroups;
  int gid = blockIdx.x;
  if (gid >= total) return;
  // bijective round-robin -> chunked remap (8 XCDs), b-major chunks
  int q = total >> 3, rr = total & 7;
  int xcd = gid & 7, lid = gid >> 3;
  int wid = (xcd < rr) ? (xcd * (q + 1) + lid)
                       : (rr * (q + 1) + (xcd - rr) * q + lid);
  int tg = wid % tgroups; int b = wid / tgroups;
  int wv = threadIdx.x >> 6;
  int l = threadIdx.x & 63;
  int lr = l & 15, lk = l >> 4;

  int ti = tg * TPB + wv / NCO;
  int c  = wv % NCO;
  if (ti >= tiles) return;

  int t = ti * 16 + lr;
  bool valid = (t < Tout);
  unsigned tt = valid ? (unsigned)t : 0u;
  unsigned h = tt / (unsigned)W;
  unsigned w = tt - h * (unsigned)W;

  // kh taps that touch any real row for this tile's h-span
  int h0 = (ti * 16) / W;
  int tl5 = ti * 16 + 15; if (tl5 >= Tout) tl5 = Tout - 1;
  int h1 = tl5 / W;
  int kh_lo = (h1 >= 5) ? 0 : 5 - h1;
  int kh_hi = (H + 4 - h0 < 10) ? (H + 4 - h0) : 10;

  const unsigned short* pB =
      Pin + ((size_t)(b * (H + 10) + h) * PW + w) * CIN + lk * 8;
  const unsigned short* pAc =
      Wt + (size_t)c * 16 * CIN + (size_t)lr * CIN + lk * 8;

  f32x4 acc0 = f32x4{0.f, 0.f, 0.f, 0.f};
  f32x4 acc1 = f32x4{0.f, 0.f, 0.f, 0.f};

  for (int kh = kh_lo; kh <= kh_hi; ++kh) {
    const unsigned short* pBr = pB + (size_t)kh * PW * CIN;
    const unsigned short* pA = pAc + (size_t)(kh * 11) * COUT * CIN;
    // batch-load ALL fragments for this kh (22 or 44 independent loads)
    bf16x8 bfr[NS][11], afr[NS][11];
#pragma unroll
    for (int s = 0; s < NS; ++s) {
#pragma unroll
      for (int kw = 0; kw < 11; ++kw) {
        bfr[s][kw] = *(const bf16x8*)(const void*)(pBr + kw * CIN + s * 32);
        afr[s][kw] = *(const bf16x8*)(const void*)(pA + (size_t)kw * COUT * CIN + s * 32);
      }
    }
    // MFMA chain split over two accumulators (even/odd kw)
#pragma unroll
    for (int s = 0; s < NS; ++s) {
#pragma unroll
      for (int kw = 0; kw < 11; ++kw) {
        if (kw & 1)
          acc1 = __builtin_amdgcn_mfma_f32_16x16x32_bf16(afr[s][kw], bfr[s][kw], acc1, 0, 0, 0);
        else
          acc0 = __builtin_amdgcn_mfma_f32_16x16x32_bf16(afr[s][kw], bfr[s][kw], acc0, 0, 0, 0);
      }
    }
  }

  if (!valid) return;
  f32x4 acc = acc0 + acc1;
  int co0 = c * 16 + lk * 4;
  float v[4];
#pragma unroll
  for (int q2 = 0; q2 < 4; ++q2) {
    float s = acc[q2] + bias[co0 + q2];
    if (MODE == 0) s = 0.5f * s * (1.0f + erff(s * 0.70710678118654752f));
    v[q2] = s;
  }
  if (MODE == 0) {
    unsigned short* Po = (unsigned short*)outp;
    size_t oa = ((size_t)(b * (H + 10) + h + 5) * PW + (w + 5)) * COUT + co0;
    uint2 pk;
    pk.x = (unsigned int)f2b(v[0]) | ((unsigned int)f2b(v[1]) << 16);
    pk.y = (unsigned int)f2b(v[2]) | ((unsigned int)f2b(v[3]) << 16);
    *(uint2*)(void*)(Po + oa) = pk;
  } else {
    float* Fo = (float*)outp;
    size_t oa = ((size_t)b * HWcap + t) * COUT + co0;
    f32x4 vv = {v[0], v[1], v[2], v[3]};
    *(f32x4*)(void*)(Fo + oa) = vv;
  }
}

__global__ void k_combine(const float* __restrict__ WRC2, const float* __restrict__ w_scale,
                          const float* __restrict__ b_scale, const float* __restrict__ POUT2,
                          const float* __restrict__ pw, const float* __restrict__ xT,
                          float* __restrict__ out1T) {
  int b = blockIdx.y;
  int tid = threadIdx.x;
  int n = tid & 31;
  int t = blockIdx.x * 8 + (tid >> 5);
  float wv = b_scale[n];
#pragma unroll
  for (int s = 0; s < 8; ++s)
    wv += WRC2[((size_t)(b * 5376 + s * 672 + t)) * 32 + n] * w_scale[n * 8 + s];
  float p0 = pw[b * 3 + 0], p1 = pw[b * 3 + 1], p2 = pw[b * 3 + 2];
  size_t bi = (size_t)(b * 1344 + t) * 32 + n;
  float rs = p0 * POUT2[bi] + p1 * POUT2[344064 + bi] + p2 * POUT2[688128 + bi];
  const float pc10 = 1.0f / 1024.0f;
  out1T[(b * 32 + n) * 672 + t] =
      (1.0f - pc10) * wv + pc10 * rs + xT[(b * 32 + n) * 672 + t];
}

__global__ void k_dct_ln(const float* __restrict__ out1T, const float* __restrict__ dcttab,
                         const float* __restrict__ ln_w, const float* __restrict__ ln_b,
                         float* __restrict__ ln) {
  int c = blockIdx.x, b = blockIdx.y;
  __shared__ float row[672];
  __shared__ float tab[2688];
  __shared__ float s1[4], s2[4];
  int tid = threadIdx.x;
  for (int i = tid; i < 672; i += 256) row[i] = out1T[(b * 32 + c) * 672 + i];
  for (int i = tid; i < 2688; i += 256) tab[i] = dcttab[i];
  __syncthreads();
  float fv[3];
  float sum = 0.f, sumsq = 0.f;
#pragma unroll
  for (int r = 0; r < 3; ++r) {
    int k = tid + r * 256;
    float acc = 0.f;
    if (k < 672) {
      int idx = k;
      int stp = (2 * k) % 2688;
      for (int m = 0; m < 672; ++m) {
        acc += row[m] * tab[idx];
        idx += stp;
        if (idx >= 2688) idx -= 2688;
      }
      acc *= 2.0f;
      sum += acc;
      sumsq += acc * acc;
    }
    fv[r] = acc;
  }
  for (int off = 32; off >= 1; off >>= 1) {
    sum += __shfl_xor(sum, off);
    sumsq += __shfl_xor(sumsq, off);
  }
  if ((tid & 63) == 0) { s1[tid >> 6] = sum; s2[tid >> 6] = sumsq; }
  __syncthreads();
  float tsum = s1[0] + s1[1] + s1[2] + s1[3];
  float tsq = s2[0] + s2[1] + s2[2] + s2[3];
  float mu = tsum * (1.0f / 672.0f);
  float var = tsq * (1.0f / 672.0f) - mu * mu;
  float rstd = rsqrtf(var + 1e-6f);
#pragma unroll
  for (int r = 0; r < 3; ++r) {
    int k = tid + r * 256;
    if (k < 672)
      ln[(b * 32 + c) * 672 + k] = (fv[r] - mu) * rstd * ln_w[k] + ln_b[k];
  }
}

__global__ void k_fc1(const float* __restrict__ ln, const float* __restrict__ w_fc1,
                      float* __restrict__ h) {
  int d = blockIdx.x, b = blockIdx.y;
  int tid = threadIdx.x;
  __shared__ float wv[32];
  if (tid < 32) wv[tid] = w_fc1[d * 32 + tid];
  __syncthreads();
  for (int t = tid; t < 672; t += 256) {
    float s = 0.f;
#pragma unroll
    for (int c = 0; c < 32; ++c) s += ln[(b * 32 + c) * 672 + t] * wv[c];
    h[(b * 64 + d) * 672 + t] = fmaxf(s, 0.f);
  }
}

__global__ void k_fc2o(const float* __restrict__ h, const float* __restrict__ w_fc2,
                       const float* __restrict__ out1T, const float* __restrict__ xT,
                       float* __restrict__ out2T) {
  int c = blockIdx.x, b = blockIdx.y;
  int tid = threadIdx.x;
  __shared__ float wv[64];
  if (tid < 64) wv[tid] = w_fc2[c * 64 + tid];
  __syncthreads();
  for (int t = tid; t < 672; t += 256) {
    float s = 0.f;
#pragma unroll
    for (int d = 0; d < 64; ++d) s += h[(b * 64 + d) * 672 + t] * wv[d];
    float lr = 1.0f / (1.0f + expf(-s));
    out2T[(b * 32 + c) * 672 + t] =
        out1T[(b * 32 + c) * 672 + t] * lr + xT[(b * 32 + c) * 672 + t];
  }
}

__global__ void k_proj(const float* __restrict__ out2T, const float* __restrict__ w_proj,
                       const float* __restrict__ b_proj, float* __restrict__ out) {
  int p = blockIdx.x, b = blockIdx.y;
  int tid = threadIdx.x;
  int n = tid & 31, half = tid >> 5;
  float acc = 0.f;
  for (int t = half; t < 672; t += 2)
    acc += out2T[(b * 32 + n) * 672 + t] * w_proj[p * 672 + t];
  acc += __shfl_xor(acc, 32);
  if (tid < 32) out[(b * 336 + p) * 32 + n] = acc + b_proj[p];
}

extern "C" void kernel_launch(void* const* d_in, const int* in_sizes, int n_in,
                              void* d_out, int out_size, void* d_ws, size_t ws_size,
                              hipStream_t stream) {
  (void)in_sizes; (void)n_in; (void)out_size; (void)ws_size;
  const float* x      = (const float*)d_in[0];
  const float* w_inc1 = (const float*)d_in[1];
  const float* b_inc1 = (const float*)d_in[2];
  const float* w_inc2 = (const float*)d_in[3];
  const float* b_inc2 = (const float*)d_in[4];
  const float* w_scale= (const float*)d_in[5];
  const float* b_scale= (const float*)d_in[6];
  const float* ln_w   = (const float*)d_in[7];
  const float* ln_b   = (const float*)d_in[8];
  const float* w_fc1  = (const float*)d_in[9];
  const float* w_fc2  = (const float*)d_in[10];
  const float* w_proj = (const float*)d_in[11];
  const float* b_proj = (const float*)d_in[12];
  float* out = (float*)d_out;

  char* ws = (char*)d_ws;
  double* dtabc = (double*)(ws + OFF_DTABC);
  double* dtabs = (double*)(ws + OFF_DTABS);
  double* amp   = (double*)(ws + OFF_AMP);
  float* dcttab = (float*)(ws + OFF_DCT);
  float* dfilt  = (float*)(ws + OFF_DFILT);
  float* pw     = (float*)(ws + OFF_PW);
  int*   meta   = (int*)(ws + OFF_META);
  float* B1     = (float*)(ws + OFF_B1);
  float* B2     = (float*)(ws + OFF_B2);
  unsigned short* W1T = (unsigned short*)(ws + OFF_W1T);
  unsigned short* W2T = (unsigned short*)(ws + OFF_W2T);
  float* xT     = (float*)(ws + OFF_XT);
  unsigned short* PADW  = (unsigned short*)(ws + OFF_PADW);
  unsigned short* PADW2 = (unsigned short*)(ws + OFF_PADW2);
  unsigned short* PADP  = (unsigned short*)(ws + OFF_PADP);
  unsigned short* PADP2 = (unsigned short*)(ws + OFF_PADP2);
  float* WRC2  = (float*)(ws + OFF_WRC2);
  float* POUT2 = (float*)(ws + OFF_POUT2);
  float* out1T = (float*)(ws + OFF_OUT1T);
  float* lnb   = (float*)(ws + OFF_LN);
  float* hb    = (float*)(ws + OFF_HB);
  float* out2T = (float*)(ws + OFF_OUT2T);

  // host-side CWT geometry (replicates numpy double arithmetic)
  CwtP P;
  const double step = 16.0 / 1023.0;
  for (int i = 0; i < 8; ++i) {
    double e = (i == 7) ? 4.0 : (-1.0 + (double)i * (5.0 / 7.0));
    double s = pow(2.0, e);
    double sstep = s * step;
    int Na = (int)ceil(16.0 * s + 1.0);
    int L = 0;
    for (int k = 0; k < Na; ++k) {
      long j = (long)((double)k / sstep);
      if (j < 1024) L++;
      else break;
    }
    P.sstep[i] = sstep;
    P.L[i] = L;
    P.st0[i] = (L - 2) / 2;
    P.sqs[i] = (float)sqrt(s);
  }

  k_tables<<<1, 256, 0, stream>>>(dtabc, dtabs, dcttab);
  k_wmeanb<<<(247808 + 96 + 255) / 256, 256, 0, stream>>>(w_inc1, b_inc1, w_inc2, b_inc2,
                                                          W1T, W2T, B1, B2);
  k_xT<<<672, 256, 0, stream>>>(x, xT);
  k_dfilt<<<1, 1024, 0, stream>>>(dfilt, P);
  k_dft<<<dim3(337, 8), 64, 0, stream>>>(x, dtabc, dtabs, amp);
  k_top<<<1, 64, 0, stream>>>(amp, meta, pw);

  // wavelet branch: H=8, W=672 -> conv1: 8*336 blocks; conv2: 8*168 blocks
  k_zero<<<2048, 256, 0, stream>>>((float4*)(ws + OFF_PADW), 1178496);  // PADW+PADW2
  k_cwt<<<dim3(8, 32, 8), 256, 0, stream>>>(xT, dfilt, PADW, P);
  k_conv<32, 64, 0><<<2688, 256, 0, stream>>>(PADW, W1T, B1, (void*)PADW2,
                                              8, 672, -1, meta, 0, 1 << 30);
  k_conv<64, 32, 1><<<1344, 256, 0, stream>>>(PADW2, W2T, B2, (void*)WRC2,
                                              8, 672, -1, meta, 5376, 1 << 30);

  // period branch: conv1 <= 8*84=672 blocks; conv2 = 8*21=168 (t<672)
  for (int k = 0; k < 3; ++k) {
    k_zero<<<1024, 256, 0, stream>>>((float4*)(ws + OFF_PADP), 240064);
    k_zero<<<2048, 256, 0, stream>>>((float4*)(ws + OFF_PADP2), 480128);
    k_pfill<<<672, 256, 0, stream>>>(x, PADP, meta, k);
    k_conv<32, 64, 0><<<672, 256, 0, stream>>>(PADP, W1T, B1, (void*)PADP2,
                                               0, 0, k, meta, 0, 1 << 30);
    k_conv<64, 32, 1><<<168, 256, 0, stream>>>(PADP2, W2T, B2,
                                               (void*)(POUT2 + (size_t)k * 344064),
                                               0, 0, k, meta, 1344, 672);
  }

  k_combine<<<dim3(84, 8), 256, 0, stream>>>(WRC2, w_scale, b_scale, POUT2, pw, xT, out1T);
  k_dct_ln<<<dim3(32, 8), 256, 0, stream>>>(out1T, dcttab, ln_w, ln_b, lnb);
  k_fc1<<<dim3(64, 8), 256, 0, stream>>>(lnb, w_fc1, hb);
  k_fc2o<<<dim3(32, 8), 256, 0, stream>>>(hb, w_fc2, out1T, xT, out2T);
  k_proj<<<dim3(336, 8), 64, 0, stream>>>(out2T, w_proj, b_proj, out);
}

// Round 12
// 910.544 us; speedup vs baseline: 1.2280x; 1.2184x over previous
//
#include <hip/hip_runtime.h>
#include <math.h>

#ifndef M_PI
#define M_PI 3.14159265358979323846
#endif

typedef __attribute__((ext_vector_type(8))) short bf16x8;
typedef __attribute__((ext_vector_type(4))) float f32x4;

struct CwtP {
  double sstep[8];
  float  sqs[8];
  int    L[8];
  int    st0[8];
};

// ---- workspace byte-offset map (high-water ~30.9 MB) ----
#define OFF_DTABC 0
#define OFF_DTABS 5376
#define OFF_AMP   10752
#define OFF_DCT   32320
#define OFF_DFILT 43072
#define OFF_PW    51520
#define OFF_META  51616
#define OFF_B1    51712
#define OFF_B2    51968
#define OFF_W1T   52224
#define OFF_W2T   547840
#define OFF_XT    1043456
#define OFF_PADW  1731584
#define OFF_PADW2 8016896
#define OFF_WRC2  20587520
#define OFF_POUT2 26092544
#define OFF_OUT1T 30221312
// aliases (live ranges disjoint):
#define OFF_PADP  OFF_PADW
#define OFF_PADP2 OFF_PADW2
#define OFF_LN    26092544
#define OFF_HB    26780672
#define OFF_OUT2T 28156928

__device__ inline unsigned short f2b(float f) {
  unsigned int u = __float_as_uint(f);
  unsigned int r = (u + 0x7fffu + ((u >> 16) & 1u)) >> 16;
  return (unsigned short)r;
}

__global__ void k_tables(double* __restrict__ dtabc, double* __restrict__ dtabs,
                         float* __restrict__ dcttab) {
  int tid = threadIdx.x;
  for (int j = tid; j < 672; j += blockDim.x) {
    double a = (2.0 * M_PI * (double)j) / 672.0;
    dtabc[j] = cos(a);
    dtabs[j] = sin(a);
  }
  for (int j = tid; j < 2688; j += blockDim.x) {
    dcttab[j] = (float)cos(M_PI * (double)j / 1344.0);
  }
}

// mean-of-6 masked weights -> bf16 tap-major layouts:
// W1T[tap][co(64)][ci(32)], W2T[tap][co(32)][ci(64)]; biases fp32
__global__ void k_wmeanb(const float* __restrict__ w1, const float* __restrict__ b1,
                         const float* __restrict__ w2, const float* __restrict__ b2,
                         unsigned short* __restrict__ W1T, unsigned short* __restrict__ W2T,
                         float* __restrict__ B1, float* __restrict__ B2) {
  int i = blockIdx.x * blockDim.x + threadIdx.x;
  const float inv6 = 1.0f / 6.0f;
  if (i < 247808) {
    float s1 = 0.f, s2 = 0.f;
#pragma unroll
    for (int g = 0; g < 6; ++g) { s1 += w1[g * 247808 + i]; s2 += w2[g * 247808 + i]; }
    s1 *= inv6; s2 *= inv6;
    {
      int co = i / 3872; int r = i - co * 3872;
      int ci = r / 121;  int tap = r - ci * 121;
      W1T[tap * 2048 + co * 32 + ci] = f2b(s1);
    }
    {
      int co = i / 7744; int r = i - co * 7744;
      int ci = r / 121;  int tap = r - ci * 121;
      W2T[tap * 2048 + co * 64 + ci] = f2b(s2);
    }
  } else {
    int j = i - 247808;
    if (j < 64) {
      float s = 0.f;
#pragma unroll
      for (int g = 0; g < 6; ++g) s += b1[g * 64 + j];
      B1[j] = s * inv6;
    } else if (j < 96) {
      int c = j - 64;
      float s = 0.f;
#pragma unroll
      for (int g = 0; g < 6; ++g) s += b2[g * 32 + c];
      B2[c] = s * inv6;
    }
  }
}

__global__ void k_xT(const float* __restrict__ x, float* __restrict__ xT) {
  int i = blockIdx.x * 256 + threadIdx.x;
  if (i >= 8 * 672 * 32) return;
  int n = i & 31;
  int t = (i >> 5) % 672;
  int b = i / (32 * 672);
  xT[(b * 32 + n) * 672 + t] = x[i];
}

__global__ void k_dft(const float* __restrict__ x, const double* __restrict__ tc,
                      const double* __restrict__ ts, double* __restrict__ amp) {
  int k = blockIdx.x, b = blockIdx.y;
  int tid = threadIdx.x;
  int n = tid & 31, half = tid >> 5;
  double re = 0.0, im = 0.0;
  for (int t = half; t < 672; t += 2) {
    double xv = (double)x[(b * 672 + t) * 32 + n];
    int idx = (k * t) % 672;
    re += xv * tc[idx];
    im += xv * ts[idx];
  }
  re += __shfl_xor(re, 32);
  im += __shfl_xor(im, 32);
  double a = sqrt(re * re + im * im);
  for (int off = 16; off >= 1; off >>= 1) a += __shfl_xor(a, off);
  if (tid == 0) amp[b * 337 + k] = a * (1.0 / 32.0);
}

__global__ void k_top(const double* __restrict__ amp, int* __restrict__ meta,
                      float* __restrict__ pw) {
  __shared__ double fr[337];
  __shared__ int sidx[3];
  int tid = threadIdx.x;
  for (int k = tid; k < 337; k += 64) {
    double s = 0.0;
    for (int b = 0; b < 8; ++b) s += amp[b * 337 + k];
    fr[k] = (k == 0) ? -1.0 : s * 0.125;
  }
  __syncthreads();
  if (tid == 0) {
    for (int r = 0; r < 3; ++r) {
      int best = 1; double bv = fr[1];
      for (int k = 2; k < 337; ++k) if (fr[k] > bv) { bv = fr[k]; best = k; }
      fr[best] = -2.0;
      sidx[r] = best;
      meta[r] = best;
      int p = 672 / best;
      meta[3 + r] = p;                     // W
      int len = (672 % p == 0) ? 672 : (672 / p + 1) * p;
      meta[6 + r] = len;
      meta[9 + r] = len / p;               // H
    }
  }
  __syncthreads();
  if (tid < 8) {
    int b = tid;
    float v0 = (float)amp[b * 337 + sidx[0]];
    float v1 = (float)amp[b * 337 + sidx[1]];
    float v2 = (float)amp[b * 337 + sidx[2]];
    float m = fmaxf(v0, fmaxf(v1, v2));
    float e0 = expf(v0 - m), e1 = expf(v1 - m), e2 = expf(v2 - m);
    float inv = 1.0f / (e0 + e1 + e2);
    pw[b * 3 + 0] = e0 * inv;
    pw[b * 3 + 1] = e1 * inv;
    pw[b * 3 + 2] = e2 * inv;
  }
}

// parallel psi integration: 1024 threads, Hillis-Steele scan in LDS
__global__ void k_dfilt(float* __restrict__ dfilt, CwtP P) {
  __shared__ double ipsi[1024];
  int tid = threadIdx.x;
  const double step = 16.0 / 1023.0;
  double xg = (tid == 1023) ? 8.0 : (-8.0 + (double)tid * step);
  ipsi[tid] = exp(-0.5 * xg * xg) * cos(5.0 * xg);
  __syncthreads();
  for (int off = 1; off < 1024; off <<= 1) {
    double v = ipsi[tid];
    double a = (tid >= off) ? ipsi[tid - off] : 0.0;
    __syncthreads();
    ipsi[tid] = v + a;
    __syncthreads();
  }
  for (int s = 0; s < 8; ++s) {
    int L = P.L[s];
    double sstep = P.sstep[s];
    for (int q = tid; q <= L; q += 1024) {
      float fq = 0.f, fqm = 0.f;
      if (q < L)  { long j = (long)((double)(L - 1 - q) / sstep); fq  = (float)(ipsi[j] * step); }
      if (q >= 1) { long j = (long)((double)(L - q) / sstep);     fqm = (float)(ipsi[j] * step); }
      dfilt[s * 264 + q] = fq - fqm;
    }
  }
}

// CWT -> zero-padded bf16 image PADW[b][s+5][t+5][n], PH=18, PW=682
__global__ void k_cwt(const float* __restrict__ xT, const float* __restrict__ dfilt,
                      unsigned short* __restrict__ PADW, CwtP P) {
  int s = blockIdx.x, n = blockIdx.y, b = blockIdx.z;
  __shared__ float row[672];
  __shared__ float df[264];
  int tid = threadIdx.x;
  int L = P.L[s], st0 = P.st0[s];
  float sq = P.sqs[s];
  for (int i = tid; i < 672; i += blockDim.x) row[i] = xT[(b * 32 + n) * 672 + i];
  for (int i = tid; i <= L; i += blockDim.x) df[i] = dfilt[s * 264 + i];
  __syncthreads();
  for (int t = tid; t < 672; t += blockDim.x) {
    float acc = 0.f;
    int base = t + st0 + 1;
    for (int q = 0; q <= L; ++q) {
      int idx = base - q;
      if (idx >= 0 && idx < 672) acc += df[q] * row[idx];
    }
    PADW[((size_t)(b * 18 + s + 5) * 682 + (t + 5)) * 32 + n] = f2b(-sq * acc);
  }
}

__global__ void k_zero(float4* __restrict__ p, int n16) {
  int i = blockIdx.x * 256 + threadIdx.x;
  int stride = gridDim.x * 256;
  for (; i < n16; i += stride) p[i] = float4{0.f, 0.f, 0.f, 0.f};
}

// fold x into zero-padded bf16 period image: PADP[b][h+5][w+5][ci], PW=W+10
__global__ void k_pfill(const float* __restrict__ x, unsigned short* __restrict__ PADP,
                        const int* __restrict__ meta, int k) {
  int i = blockIdx.x * 256 + threadIdx.x;
  if (i >= 8 * 672 * 32) return;
  int W = meta[3 + k], H = meta[9 + k];
  int PW = W + 10;
  int ci = i & 31;
  int t = (i >> 5) % 672;
  int b = i / 21504;
  int h = t / W, w = t - h * W;
  PADP[((size_t)(b * (H + 10) + h + 5) * PW + (w + 5)) * 32 + ci] = f2b(x[i]);
}

// Tap-decomposed implicit-GEMM conv via MFMA bf16, FLAT tiling, split-kh
// across the 4 waves, NB position-tiles per wave (A-fragment reuse), and
// amdgpu_waves_per_eu(2,4): capping max occupancy at 4 waves/EU grants the
// scheduler a ~128-VGPR budget (launch_bounds' min-waves arg could NOT do
// this - rounds 8-11 all pinned at ~50 VGPR with loads sunk 1-per-MFMA).
// NB=2 additionally shares each A (weight) fragment across 2 MFMAs:
// loads/MFMA 1.5 -> 0.75 (conv1) / 1.0 (conv2), 2x independent acc chains.
// LDS reduction uses odd stride (conflict-free, measured 0 in round 9).
// MODE 0: +bias, exact GELU, write bf16 into padded mid image [b][h+5][w+5][co]
// MODE 1: +bias, write fp32 flat [b][t][co] (t < Tlim only)
template <int CIN, int COUT, int MODE, int NB>
__global__ __launch_bounds__(256) __attribute__((amdgpu_waves_per_eu(2, 4)))
void k_conv(
    const unsigned short* __restrict__ Pin, const unsigned short* __restrict__ Wt,
    const float* __restrict__ bias, void* __restrict__ outp,
    int Hs, int Ws, int gi, const int* __restrict__ meta, int HWcap, int Tlim) {
  constexpr int NA = COUT / 16;        // co tiles
  constexpr int NS = CIN / 32;         // k slices per tap
  constexpr int RED = NB * NA * 4 + 1; // odd stride -> conflict-free
  __shared__ float red[4][64][RED];

  int H = Hs, W = Ws;
  if (gi >= 0) { W = meta[3 + gi]; H = meta[9 + gi]; }
  int PW = W + 10;
  int HW = H * W;
  int Tout = (HW < Tlim) ? HW : Tlim;
  int tiles = (Tout + 15) >> 4;
  int tgroups = (tiles + NB - 1) / NB;
  int total = 8 * tgroups;
  int gid = blockIdx.x;
  if (gid >= total) return;
  // bijective round-robin -> chunked remap (8 XCDs), b-major chunks
  int q = total >> 3, rr = total & 7;
  int xcd = gid & 7, lid = gid >> 3;
  int wid = (xcd < rr) ? (xcd * (q + 1) + lid)
                       : (rr * (q + 1) + (xcd - rr) * q + lid);
  int tg = wid % tgroups; int b = wid / tgroups;
  int wv = threadIdx.x >> 6;
  int l = threadIdx.x & 63;
  int lr = l & 15, lk = l >> 4;
  int ti0 = tg * NB;

  bool val[NB];
  unsigned hj[NB], wj[NB];
  const unsigned short* pB[NB];
#pragma unroll
  for (int j = 0; j < NB; ++j) {
    int t = (ti0 + j) * 16 + lr;
    bool v = (t < Tout);
    val[j] = v;
    unsigned tt = v ? (unsigned)t : 0u;
    hj[j] = tt / (unsigned)W;
    wj[j] = tt - hj[j] * (unsigned)W;
    pB[j] = Pin + ((size_t)(b * (H + 10) + hj[j]) * PW + wj[j]) * CIN + lk * 8;
  }

  // kh taps touching any real row in this block's position span
  int h0 = (ti0 * 16) / W;
  int tlast = (ti0 + NB) * 16 - 1; if (tlast >= Tout) tlast = Tout - 1;
  int h1 = tlast / W;
  int kh_lo = (h1 >= 5) ? 0 : 5 - h1;
  int kh_hi = (H + 4 - h0 < 10) ? (H + 4 - h0) : 10;

  f32x4 acc[NA][NB];
#pragma unroll
  for (int c = 0; c < NA; ++c)
#pragma unroll
    for (int j = 0; j < NB; ++j) acc[c][j] = f32x4{0.f, 0.f, 0.f, 0.f};

  for (int kh = kh_lo + wv; kh <= kh_hi; kh += 4) {
    const unsigned short* pA =
        Wt + (size_t)(kh * 11) * COUT * CIN + (size_t)lr * CIN + lk * 8;
#pragma unroll
    for (int s = 0; s < NS; ++s) {
      bf16x8 bfr[NB][11];
#pragma unroll
      for (int j = 0; j < NB; ++j)
#pragma unroll
        for (int kw = 0; kw < 11; ++kw)
          bfr[j][kw] = *(const bf16x8*)(const void*)(
              pB[j] + (size_t)kh * PW * CIN + kw * CIN + s * 32);
#pragma unroll
      for (int kw = 0; kw < 11; ++kw) {
#pragma unroll
        for (int c = 0; c < NA; ++c) {
          bf16x8 af = *(const bf16x8*)(const void*)(
              pA + (size_t)kw * COUT * CIN + c * 16 * CIN + s * 32);
#pragma unroll
          for (int j = 0; j < NB; ++j)
            acc[c][j] = __builtin_amdgcn_mfma_f32_16x16x32_bf16(af, bfr[j][kw],
                                                                acc[c][j], 0, 0, 0);
        }
      }
    }
  }

#pragma unroll
  for (int c = 0; c < NA; ++c)
#pragma unroll
    for (int j = 0; j < NB; ++j)
#pragma unroll
      for (int q2 = 0; q2 < 4; ++q2)
        red[wv][l][(c * NB + j) * 4 + q2] = acc[c][j][q2];
  __syncthreads();

  if (wv >= NA) return;
  int c = wv;
  int co0 = c * 16 + lk * 4;
#pragma unroll
  for (int j = 0; j < NB; ++j) {
    if (!val[j]) continue;
    int t = (ti0 + j) * 16 + lr;
    float v[4];
#pragma unroll
    for (int q2 = 0; q2 < 4; ++q2) {
      float s = red[0][l][(c * NB + j) * 4 + q2] + red[1][l][(c * NB + j) * 4 + q2] +
                red[2][l][(c * NB + j) * 4 + q2] + red[3][l][(c * NB + j) * 4 + q2];
      s += bias[co0 + q2];
      if (MODE == 0) s = 0.5f * s * (1.0f + erff(s * 0.70710678118654752f));
      v[q2] = s;
    }
    if (MODE == 0) {
      unsigned short* Po = (unsigned short*)outp;
      size_t oa = ((size_t)(b * (H + 10) + hj[j] + 5) * PW + (wj[j] + 5)) * COUT + co0;
      uint2 pk;
      pk.x = (unsigned int)f2b(v[0]) | ((unsigned int)f2b(v[1]) << 16);
      pk.y = (unsigned int)f2b(v[2]) | ((unsigned int)f2b(v[3]) << 16);
      *(uint2*)(void*)(Po + oa) = pk;
    } else {
      float* Fo = (float*)outp;
      size_t oa = ((size_t)b * HWcap + t) * COUT + co0;
      f32x4 vv = {v[0], v[1], v[2], v[3]};
      *(f32x4*)(void*)(Fo + oa) = vv;
    }
  }
}

__global__ void k_combine(const float* __restrict__ WRC2, const float* __restrict__ w_scale,
                          const float* __restrict__ b_scale, const float* __restrict__ POUT2,
                          const float* __restrict__ pw, const float* __restrict__ xT,
                          float* __restrict__ out1T) {
  int b = blockIdx.y;
  int tid = threadIdx.x;
  int n = tid & 31;
  int t = blockIdx.x * 8 + (tid >> 5);
  float wv = b_scale[n];
#pragma unroll
  for (int s = 0; s < 8; ++s)
    wv += WRC2[((size_t)(b * 5376 + s * 672 + t)) * 32 + n] * w_scale[n * 8 + s];
  float p0 = pw[b * 3 + 0], p1 = pw[b * 3 + 1], p2 = pw[b * 3 + 2];
  size_t bi = (size_t)(b * 1344 + t) * 32 + n;
  float rs = p0 * POUT2[bi] + p1 * POUT2[344064 + bi] + p2 * POUT2[688128 + bi];
  const float pc10 = 1.0f / 1024.0f;
  out1T[(b * 32 + n) * 672 + t] =
      (1.0f - pc10) * wv + pc10 * rs + xT[(b * 32 + n) * 672 + t];
}

__global__ void k_dct_ln(const float* __restrict__ out1T, const float* __restrict__ dcttab,
                         const float* __restrict__ ln_w, const float* __restrict__ ln_b,
                         float* __restrict__ ln) {
  int c = blockIdx.x, b = blockIdx.y;
  __shared__ float row[672];
  __shared__ float tab[2688];
  __shared__ float s1[4], s2[4];
  int tid = threadIdx.x;
  for (int i = tid; i < 672; i += 256) row[i] = out1T[(b * 32 + c) * 672 + i];
  for (int i = tid; i < 2688; i += 256) tab[i] = dcttab[i];
  __syncthreads();
  float fv[3];
  float sum = 0.f, sumsq = 0.f;
#pragma unroll
  for (int r = 0; r < 3; ++r) {
    int k = tid + r * 256;
    float acc = 0.f;
    if (k < 672) {
      int idx = k;
      int stp = (2 * k) % 2688;
      for (int m = 0; m < 672; ++m) {
        acc += row[m] * tab[idx];
        idx += stp;
        if (idx >= 2688) idx -= 2688;
      }
      acc *= 2.0f;
      sum += acc;
      sumsq += acc * acc;
    }
    fv[r] = acc;
  }
  for (int off = 32; off >= 1; off >>= 1) {
    sum += __shfl_xor(sum, off);
    sumsq += __shfl_xor(sumsq, off);
  }
  if ((tid & 63) == 0) { s1[tid >> 6] = sum; s2[tid >> 6] = sumsq; }
  __syncthreads();
  float tsum = s1[0] + s1[1] + s1[2] + s1[3];
  float tsq = s2[0] + s2[1] + s2[2] + s2[3];
  float mu = tsum * (1.0f / 672.0f);
  float var = tsq * (1.0f / 672.0f) - mu * mu;
  float rstd = rsqrtf(var + 1e-6f);
#pragma unroll
  for (int r = 0; r < 3; ++r) {
    int k = tid + r * 256;
    if (k < 672)
      ln[(b * 32 + c) * 672 + k] = (fv[r] - mu) * rstd * ln_w[k] + ln_b[k];
  }
}

__global__ void k_fc1(const float* __restrict__ ln, const float* __restrict__ w_fc1,
                      float* __restrict__ h) {
  int d = blockIdx.x, b = blockIdx.y;
  int tid = threadIdx.x;
  __shared__ float wv[32];
  if (tid < 32) wv[tid] = w_fc1[d * 32 + tid];
  __syncthreads();
  for (int t = tid; t < 672; t += 256) {
    float s = 0.f;
#pragma unroll
    for (int c = 0; c < 32; ++c) s += ln[(b * 32 + c) * 672 + t] * wv[c];
    h[(b * 64 + d) * 672 + t] = fmaxf(s, 0.f);
  }
}

__global__ void k_fc2o(const float* __restrict__ h, const float* __restrict__ w_fc2,
                       const float* __restrict__ out1T, const float* __restrict__ xT,
                       float* __restrict__ out2T) {
  int c = blockIdx.x, b = blockIdx.y;
  int tid = threadIdx.x;
  __shared__ float wv[64];
  if (tid < 64) wv[tid] = w_fc2[c * 64 + tid];
  __syncthreads();
  for (int t = tid; t < 672; t += 256) {
    float s = 0.f;
#pragma unroll
    for (int d = 0; d < 64; ++d) s += h[(b * 64 + d) * 672 + t] * wv[d];
    float lr = 1.0f / (1.0f + expf(-s));
    out2T[(b * 32 + c) * 672 + t] =
        out1T[(b * 32 + c) * 672 + t] * lr + xT[(b * 32 + c) * 672 + t];
  }
}

__global__ void k_proj(const float* __restrict__ out2T, const float* __restrict__ w_proj,
                       const float* __restrict__ b_proj, float* __restrict__ out) {
  int p = blockIdx.x, b = blockIdx.y;
  int tid = threadIdx.x;
  int n = tid & 31, half = tid >> 5;
  float acc = 0.f;
  for (int t = half; t < 672; t += 2)
    acc += out2T[(b * 32 + n) * 672 + t] * w_proj[p * 672 + t];
  acc += __shfl_xor(acc, 32);
  if (tid < 32) out[(b * 336 + p) * 32 + n] = acc + b_proj[p];
}

extern "C" void kernel_launch(void* const* d_in, const int* in_sizes, int n_in,
                              void* d_out, int out_size, void* d_ws, size_t ws_size,
                              hipStream_t stream) {
  (void)in_sizes; (void)n_in; (void)out_size; (void)ws_size;
  const float* x      = (const float*)d_in[0];
  const float* w_inc1 = (const float*)d_in[1];
  const float* b_inc1 = (const float*)d_in[2];
  const float* w_inc2 = (const float*)d_in[3];
  const float* b_inc2 = (const float*)d_in[4];
  const float* w_scale= (const float*)d_in[5];
  const float* b_scale= (const float*)d_in[6];
  const float* ln_w   = (const float*)d_in[7];
  const float* ln_b   = (const float*)d_in[8];
  const float* w_fc1  = (const float*)d_in[9];
  const float* w_fc2  = (const float*)d_in[10];
  const float* w_proj = (const float*)d_in[11];
  const float* b_proj = (const float*)d_in[12];
  float* out = (float*)d_out;

  char* ws = (char*)d_ws;
  double* dtabc = (double*)(ws + OFF_DTABC);
  double* dtabs = (double*)(ws + OFF_DTABS);
  double* amp   = (double*)(ws + OFF_AMP);
  float* dcttab = (float*)(ws + OFF_DCT);
  float* dfilt  = (float*)(ws + OFF_DFILT);
  float* pw     = (float*)(ws + OFF_PW);
  int*   meta   = (int*)(ws + OFF_META);
  float* B1     = (float*)(ws + OFF_B1);
  float* B2     = (float*)(ws + OFF_B2);
  unsigned short* W1T = (unsigned short*)(ws + OFF_W1T);
  unsigned short* W2T = (unsigned short*)(ws + OFF_W2T);
  float* xT     = (float*)(ws + OFF_XT);
  unsigned short* PADW  = (unsigned short*)(ws + OFF_PADW);
  unsigned short* PADW2 = (unsigned short*)(ws + OFF_PADW2);
  unsigned short* PADP  = (unsigned short*)(ws + OFF_PADP);
  unsigned short* PADP2 = (unsigned short*)(ws + OFF_PADP2);
  float* WRC2  = (float*)(ws + OFF_WRC2);
  float* POUT2 = (float*)(ws + OFF_POUT2);
  float* out1T = (float*)(ws + OFF_OUT1T);
  float* lnb   = (float*)(ws + OFF_LN);
  float* hb    = (float*)(ws + OFF_HB);
  float* out2T = (float*)(ws + OFF_OUT2T);

  // host-side CWT geometry (replicates numpy double arithmetic)
  CwtP P;
  const double step = 16.0 / 1023.0;
  for (int i = 0; i < 8; ++i) {
    double e = (i == 7) ? 4.0 : (-1.0 + (double)i * (5.0 / 7.0));
    double s = pow(2.0, e);
    double sstep = s * step;
    int Na = (int)ceil(16.0 * s + 1.0);
    int L = 0;
    for (int k = 0; k < Na; ++k) {
      long j = (long)((double)k / sstep);
      if (j < 1024) L++;
      else break;
    }
    P.sstep[i] = sstep;
    P.L[i] = L;
    P.st0[i] = (L - 2) / 2;
    P.sqs[i] = (float)sqrt(s);
  }

  k_tables<<<1, 256, 0, stream>>>(dtabc, dtabs, dcttab);
  k_wmeanb<<<(247808 + 96 + 255) / 256, 256, 0, stream>>>(w_inc1, b_inc1, w_inc2, b_inc2,
                                                          W1T, W2T, B1, B2);
  k_xT<<<672, 256, 0, stream>>>(x, xT);
  k_dfilt<<<1, 1024, 0, stream>>>(dfilt, P);
  k_dft<<<dim3(337, 8), 64, 0, stream>>>(x, dtabc, dtabs, amp);
  k_top<<<1, 64, 0, stream>>>(amp, meta, pw);

  // wavelet branch: H=8, W=672, NB=2 -> 8 * 168 groups = 1344 blocks each
  k_zero<<<2048, 256, 0, stream>>>((float4*)(ws + OFF_PADW), 1178496);  // PADW+PADW2
  k_cwt<<<dim3(8, 32, 8), 256, 0, stream>>>(xT, dfilt, PADW, P);
  k_conv<32, 64, 0, 2><<<1344, 256, 0, stream>>>(PADW, W1T, B1, (void*)PADW2,
                                                 8, 672, -1, meta, 0, 1 << 30);
  k_conv<64, 32, 1, 2><<<1344, 256, 0, stream>>>(PADW2, W2T, B2, (void*)WRC2,
                                                 8, 672, -1, meta, 5376, 1 << 30);

  // period branch: NB=1 (same grids as round 9; small data-dependent work)
  for (int k = 0; k < 3; ++k) {
    k_zero<<<1024, 256, 0, stream>>>((float4*)(ws + OFF_PADP), 240064);
    k_zero<<<2048, 256, 0, stream>>>((float4*)(ws + OFF_PADP2), 480128);
    k_pfill<<<672, 256, 0, stream>>>(x, PADP, meta, k);
    k_conv<32, 64, 0, 1><<<672, 256, 0, stream>>>(PADP, W1T, B1, (void*)PADP2,
                                                  0, 0, k, meta, 0, 1 << 30);
    k_conv<64, 32, 1, 1><<<336, 256, 0, stream>>>(PADP2, W2T, B2,
                                                  (void*)(POUT2 + (size_t)k * 344064),
                                                  0, 0, k, meta, 1344, 672);
  }

  k_combine<<<dim3(84, 8), 256, 0, stream>>>(WRC2, w_scale, b_scale, POUT2, pw, xT, out1T);
  k_dct_ln<<<dim3(32, 8), 256, 0, stream>>>(out1T, dcttab, ln_w, ln_b, lnb);
  k_fc1<<<dim3(64, 8), 256, 0, stream>>>(lnb, w_fc1, hb);
  k_fc2o<<<dim3(32, 8), 256, 0, stream>>>(hb, w_fc2, out1T, xT, out2T);
  k_proj<<<dim3(336, 8), 64, 0, stream>>>(out2T, w_proj, b_proj, out);
}